// Round 10
// baseline (388.103 us; speedup 1.0000x reference)
//
#include <hip/hip_runtime.h>
#include <hip/hip_bf16.h>
#include <stdint.h>

#define HID   2048
#define NH    16
#define QKV_N 6144   // 16*(2*128+128)
#define BT    8192   // B*T
#define TT    2048   // T

typedef short bf16x8  __attribute__((ext_vector_type(8)));
typedef float f32x4   __attribute__((ext_vector_type(4)));
typedef float f32x16  __attribute__((ext_vector_type(16)));
typedef unsigned short u16;

__device__ __forceinline__ u16 f2bf(float f){
  union { float f; unsigned u; } v; v.f = f;
  unsigned r = 0x7fffu + ((v.u >> 16) & 1u);
  return (u16)((v.u + r) >> 16);
}
__device__ __forceinline__ float bf2f(u16 x){
  union { unsigned u; float f; } v; v.u = ((unsigned)x) << 16;
  return v.f;
}
__device__ __forceinline__ unsigned cvt_pk_bf16(float lo, float hi){
  unsigned r;
  asm("v_cvt_pk_bf16_f32 %0, %1, %2" : "=v"(r) : "v"(lo), "v"(hi));
  return r;
}

typedef __attribute__((address_space(3))) void lds_vt;
typedef const __attribute__((address_space(1))) void gbl_vt;

__device__ __forceinline__ void gload16(const void* g, void* l){
  __builtin_amdgcn_global_load_lds((gbl_vt*)g, (lds_vt*)l, 16, 0, 0);
}

#define FENCE() asm volatile("" ::: "memory")
#define SYNC()  { FENCE(); __builtin_amdgcn_s_barrier(); FENCE(); }

// ---------------- fused fp32 -> bf16 convert (3 arrays, 1 launch) ----------------
__global__ __launch_bounds__(256) void cvt_all(const float* __restrict__ in1, u16* __restrict__ o1, int n1,
                                               const float* __restrict__ in2, u16* __restrict__ o2, int n2,
                                               const float* __restrict__ in3, u16* __restrict__ o3, int n3){
  int i = blockIdx.x * blockDim.x + threadIdx.x;
  const int stride = gridDim.x * blockDim.x;
  const int ntot = n1 + n2 + n3;
  for (; i < ntot; i += stride){
    const float* ip; u16* op; int k;
    if (i < n1)            { ip = in1; op = o1; k = i; }
    else if (i < n1 + n2)  { ip = in2; op = o2; k = i - n1; }
    else                   { ip = in3; op = o3; k = i - n1 - n2; }
    float4 v = ((const float4*)ip)[k];
    ushort4 o;
    o.x = f2bf(v.x); o.y = f2bf(v.y); o.z = f2bf(v.z); o.w = f2bf(v.w);
    ((ushort4*)op)[k] = o;
  }
}

// ------- 256x256 bf16 GEMM, C = A * B^T (+bias), 32x32x16 core -------
// Subtiled LDS layout: per 32-row x 64-k subtile (4KB), element (row, k=ks*16+hi*8+e)
// at byte (ks>>1)*2048 + (row&15)*128 + ((row>>4 | hi<<1 | (ks&1)<<2) ^ (row&7))*16 + e*2.
// Fragment reads then span a 16-row window with per-8-lane slot bijection ==
// the measured-conflict-free 16x16 geometry. Staging = linear global_load_lds
// with the inverse mapping applied to the per-thread GLOBAL source (rule #21).
template<int OUT_BF16>
__global__ __launch_bounds__(512, 2) void gemm256(const u16* __restrict__ A,
                                                  const u16* __restrict__ Bm,
                                                  u16* __restrict__ Cb,
                                                  float* __restrict__ Cf,
                                                  const float* __restrict__ bias,
                                                  int M, int N, int K)
{
  __shared__ u16 lds[4 * 256 * 64];   // 128 KiB
  u16* const Abuf[2] = { lds,          lds + 16384 };
  u16* const Bbuf[2] = { lds + 32768,  lds + 49152 };

  const int tid  = threadIdx.x;
  const int w    = tid >> 6;
  const int lane = tid & 63;
  const int wm   = w >> 2;          // 0..1
  const int wn   = w & 3;           // 0..3
  const int l31  = lane & 31;
  const int hi   = lane >> 5;
  const int sw7  = l31 & 7;
  const int r15  = l31 & 15;
  const int sbase = (l31 >> 4) | (hi << 1);   // 0..3

  int bid = blockIdx.x;
  { int qq = gridDim.x >> 3; bid = (bid & 7) * qq + (bid >> 3); }
  const int ntile = N >> 8;
  const int m0 = (bid / ntile) << 8;
  const int n0 = (bid % ntile) << 8;

  // staging source decode: global slot tt covers LDS half-image bytes [tt*16, +16)
  // tt = inst*512 + tid. Decode subtile/region/row/k from tt (inverse of layout).
  int rowS[2], kS[2];
  #pragma unroll
  for (int i = 0; i < 2; ++i){
    int tt  = i * 512 + tid;
    int sub = (tt >> 8) & 3;
    int rg  = (tt >> 7) & 1;
    int r   = (tt >> 3) & 15;
    int sl  = (tt & 7) ^ (r & 7);
    rowS[i] = sub * 32 + (sl & 1) * 16 + r;
    kS[i]   = (((rg << 1) | (sl >> 2)) << 4) + ((sl >> 1) & 1) * 8;
  }
  const u16* gA0 = A  + (size_t)(m0 + rowS[0]) * K + kS[0];
  const u16* gA1 = A  + (size_t)(m0 + rowS[1]) * K + kS[1];
  const u16* gB0 = Bm + (size_t)(n0 + rowS[0]) * K + kS[0];
  const u16* gB1 = Bm + (size_t)(n0 + rowS[1]) * K + kS[1];
  const int wds = w * 512;          // u16: wave chunk inside 8KB instruction image

  f32x16 acc[4][2] = {};
  bf16x8 aq[2][4], bq[2][4];

  auto stgA = [&](int buf, int half, int kt){
    gload16(gA0 + (size_t)(half * 128) * K + kt * 64, Abuf[buf] + half * 8192 + wds);
    gload16(gA1 + (size_t)(half * 128) * K + kt * 64, Abuf[buf] + half * 8192 + 4096 + wds);
  };
  auto stgB = [&](int buf, int half, int kt){
    gload16(gB0 + (size_t)(half * 128) * K + kt * 64, Bbuf[buf] + half * 8192 + wds);
    gload16(gB1 + (size_t)(half * 128) * K + kt * 64, Bbuf[buf] + half * 8192 + 4096 + wds);
  };
  // A-frag: lane holds row l31 of subtile, k = ks*16 + hi*8 + e
  auto loadA = [&](const u16* ab, int mp){
    #pragma unroll
    for (int mi = 0; mi < 2; ++mi){
      const u16* base = ab + (wm * 4 + mp * 2 + mi) * 2048 + r15 * 64;
      #pragma unroll
      for (int ks = 0; ks < 4; ++ks){
        const int slot = (sbase | ((ks & 1) << 2)) ^ sw7;
        aq[mi][ks] = *(const bf16x8*)(base + (ks >> 1) * 1024 + slot * 8);
      }
    }
  };
  auto loadB = [&](const u16* bb){
    #pragma unroll
    for (int ni = 0; ni < 2; ++ni){
      const u16* base = bb + (wn * 2 + ni) * 2048 + r15 * 64;
      #pragma unroll
      for (int ks = 0; ks < 4; ++ks){
        const int slot = (sbase | ((ks & 1) << 2)) ^ sw7;
        bq[ni][ks] = *(const bf16x8*)(base + (ks >> 1) * 1024 + slot * 8);
      }
    }
  };

#define MFMAP(MP) do {                                                        \
    __builtin_amdgcn_s_setprio(1);                                            \
    _Pragma("unroll")                                                         \
    for (int ks = 0; ks < 4; ++ks){                                           \
      _Pragma("unroll")                                                       \
      for (int mi = 0; mi < 2; ++mi){                                         \
        _Pragma("unroll")                                                     \
        for (int ni = 0; ni < 2; ++ni)                                        \
          acc[(MP)*2+mi][ni] = __builtin_amdgcn_mfma_f32_32x32x16_bf16(       \
              aq[mi][ks], bq[ni][ks], acc[(MP)*2+mi][ni], 0, 0, 0);           \
      }                                                                       \
    }                                                                         \
    __builtin_amdgcn_s_setprio(0);                                            \
  } while (0)

  // prologue: A(0), B(0) landed; B(1) outstanding (4 vm-ops)
  stgA(0, 0, 0); stgA(0, 1, 0);
  stgB(0, 0, 0); stgB(0, 1, 0);
  stgB(1, 0, 1); stgB(1, 1, 1);
  asm volatile("s_waitcnt vmcnt(4)" ::: "memory");
  SYNC();

  const int NI = K >> 7;   // 2 K-tiles per iter
  for (int it = 0; it < NI; ++it){
    const int t = it * 2;
    const bool lastI = (it == NI - 1);

    // ---- tile t (buf0), phase 1 ----
    loadB(Bbuf[0]);
    loadA(Abuf[0], 0);
    stgA(1, 0, t + 1); stgA(1, 1, t + 1);
    SYNC(); MFMAP(0); SYNC();
    // ---- tile t, phase 2 ----
    loadA(Abuf[0], 1);
    if (!lastI){ stgB(0, 0, t + 2); stgB(0, 1, t + 2); }
    SYNC(); MFMAP(1);
    if (lastI) asm volatile("s_waitcnt vmcnt(0)" ::: "memory");
    else       asm volatile("s_waitcnt vmcnt(4)" ::: "memory");
    SYNC();

    // ---- tile t+1 (buf1), phase 3 ----
    loadB(Bbuf[1]);
    loadA(Abuf[1], 0);
    if (!lastI){ stgA(0, 0, t + 2); stgA(0, 1, t + 2); }
    SYNC(); MFMAP(0); SYNC();
    // ---- tile t+1, phase 4 ----
    loadA(Abuf[1], 1);
    if (!lastI){ stgB(1, 0, t + 3); stgB(1, 1, t + 3); }
    SYNC(); MFMAP(1);
    if (!lastI) asm volatile("s_waitcnt vmcnt(4)" ::: "memory");
    SYNC();
  }
#undef MFMAP

  // epilogue: 32x32 D layout: row = (r&3) + 8*(r>>2) + 4*hi, col = l31
  #pragma unroll
  for (int mt = 0; mt < 4; ++mt)
    #pragma unroll
    for (int nt = 0; nt < 2; ++nt){
      const int col = n0 + wn * 64 + nt * 32 + l31;
      const float bs = OUT_BF16 ? 0.f : bias[col];
      #pragma unroll
      for (int r = 0; r < 16; ++r){
        const int row = m0 + wm * 128 + mt * 32 + (r & 3) + 8 * (r >> 2) + 4 * hi;
        const float v = acc[mt][nt][r];
        if (OUT_BF16)
          Cb[(size_t)row * N + col] = f2bf(v);
        else
          Cf[(size_t)row * N + col] = v + bs;
      }
    }
}

// ---------------- V transpose -> pre-swizzled tiled image ----------------
__global__ __launch_bounds__(256) void vtrans(const u16* __restrict__ qkv,
                                              u16* __restrict__ vt2){
  __shared__ u16 tile[32][136];
  const int t5 = blockIdx.x;        // kv tile (32 rows)
  const int bh = blockIdx.y;
  const int b = bh >> 4, h = bh & 15;
  const int tid = threadIdx.x;

  #pragma unroll
  for (int p = 0; p < 2; ++p){
    int idx = p * 256 + tid;
    int row = idx >> 4;             // t-row 0..31
    int c8  = (idx & 15) * 8;
    bf16x8 v = *(const bf16x8*)(qkv + (size_t)(b * TT + t5 * 32 + row) * QKV_N + 4096 + h * 128 + c8);
    *(bf16x8*)(&tile[row][c8]) = v;
  }
  __syncthreads();
  u16* outp = vt2 + (size_t)(bh * 64 + t5) * 4096;
  #pragma unroll
  for (int p = 0; p < 2; ++p){
    int id = p * 256 + tid;         // slot id 0..511
    int r  = id >> 3;               // 0..63
    int sp = id & 7;
    int sl = sp ^ (r & 7);
    int d  = (sl >> 2) * 64 + r;
    int kv = (sl & 3) * 8;
    bf16x8 v;
    #pragma unroll
    for (int e = 0; e < 8; ++e) v[e] = (short)tile[kv + e][d];
    *(bf16x8*)(outp + id * 8) = v;
  }
}

// ---------------- causal flash attention, swapped 32x32, KVBLK=32 ----------------
__global__ __launch_bounds__(256, 3) void attn(const u16* __restrict__ qkv,
                                               const u16* __restrict__ vt2,
                                               u16* __restrict__ aout)
{
  __shared__ u16 Kl[3][32 * 128];   // 24KB
  __shared__ u16 Vl[3][64 * 64];    // 24KB

  const int qt = 15 - (int)blockIdx.y;
  const int bh = blockIdx.x;
  const int b = bh >> 4, h = bh & 15;
  const int tid  = threadIdx.x;
  const int w    = tid >> 6;
  const int lane = tid & 63;
  const int l31  = lane & 31;
  const int hi   = lane >> 5;
  const int sw7  = l31 & 7;

  const int qg = qt * 128 + w * 32 + l31;   // this lane's q row
  const float sc2 = 0.08838834764831845f * 1.4426950408889634f;

  bf16x8 qf[8];
  {
    const u16* qp = qkv + (size_t)(b * TT + qg) * QKV_N + h * 128 + hi * 8;
    #pragma unroll
    for (int s = 0; s < 8; ++s){
      bf16x8 raw = *(const bf16x8*)(qp + s * 16);
      unsigned pk[4];
      #pragma unroll
      for (int p2 = 0; p2 < 4; ++p2)
        pk[p2] = cvt_pk_bf16(bf2f((u16)raw[2 * p2]) * sc2,
                             bf2f((u16)raw[2 * p2 + 1]) * sc2);
      int4 u = { (int)pk[0], (int)pk[1], (int)pk[2], (int)pk[3] };
      qf[s] = *(bf16x8*)&u;
    }
  }

  f32x16 o[4] = {};
  float lsum = 0.f;

  const u16* ksrc = qkv + (size_t)(b * TT + (tid >> 4)) * QKV_N + 2048 + h * 128
                    + (((tid & 15) ^ ((tid >> 4) & 7)) * 8);
  const u16* vsrc = vt2 + (size_t)bh * (64 * 4096) + tid * 8;

  auto stage = [&](int buf, int j){
    const u16* ks = ksrc + (size_t)(j * 32) * QKV_N;
    gload16(ks,                      &Kl[buf][tid * 8]);
    gload16(ks + (size_t)16 * QKV_N, &Kl[buf][2048 + tid * 8]);
    const u16* vs = vsrc + (size_t)j * 4096;
    gload16(vs,        &Vl[buf][tid * 8]);
    gload16(vs + 2048, &Vl[buf][2048 + tid * 8]);
  };

  const int NT  = 4 * qt + 4;       // >= 4
  const int jme = qt * 4 + w;       // last tile this wave computes (diagonal)
  stage(0, 0);
  stage(1, 1);

  int cur = 0;
  for (int j = 0; j < NT; ++j){
    SYNC();                                   // B1: buf[(j+2)%3]'s readers done
    if (j + 2 < NT){
      int nb = cur + 2; if (nb >= 3) nb -= 3;
      stage(nb, j + 2);
      asm volatile("s_waitcnt vmcnt(8)" ::: "memory");   // stage(j) landed
    } else if (j + 1 < NT){
      asm volatile("s_waitcnt vmcnt(4)" ::: "memory");
    } else {
      asm volatile("s_waitcnt vmcnt(0)" ::: "memory");
    }
    SYNC();                                   // B2: buf[cur] visible

    if (j <= jme){
      f32x16 sa = {}, sb = {};
      const u16* KB = Kl[cur];
      __builtin_amdgcn_s_setprio(1);
      #pragma unroll
      for (int sl = 0; sl < 4; ++sl){
        const int spa = ((sl * 2 + hi) ^ sw7) * 8;
        const int spb = (((sl + 4) * 2 + hi) ^ sw7) * 8;
        bf16x8 ka = *(const bf16x8*)(KB + l31 * 128 + spa);
        bf16x8 kb2 = *(const bf16x8*)(KB + l31 * 128 + spb);
        sa = __builtin_amdgcn_mfma_f32_32x32x16_bf16(ka,  qf[sl],     sa, 0, 0, 0);
        sb = __builtin_amdgcn_mfma_f32_32x32x16_bf16(kb2, qf[sl + 4], sb, 0, 0, 0);
      }
      __builtin_amdgcn_s_setprio(0);

      f32x16 s;
      #pragma unroll
      for (int r = 0; r < 16; ++r) s[r] = sa[r] + sb[r];

      if (j == jme){
        #pragma unroll
        for (int r = 0; r < 16; ++r){
          const int krow = (r & 3) + 8 * (r >> 2) + 4 * hi;
          if (krow > l31) s[r] = -3.0e38f;
        }
      }

      #pragma unroll
      for (int r = 0; r < 16; ++r) s[r] = exp2f(s[r]);
      {
        float t0 = (s[0] + s[1]) + (s[2] + s[3]);
        float t1 = (s[4] + s[5]) + (s[6] + s[7]);
        float t2 = (s[8] + s[9]) + (s[10] + s[11]);
        float t3 = (s[12] + s[13]) + (s[14] + s[15]);
        lsum += (t0 + t1) + (t2 + t3);
      }

      bf16x8 pf[2];
      #pragma unroll
      for (int kb = 0; kb < 2; ++kb){
        const int R0 = kb * 8;
        const unsigned wa0 = cvt_pk_bf16(s[R0],     s[R0 + 1]);
        const unsigned wa1 = cvt_pk_bf16(s[R0 + 2], s[R0 + 3]);
        const unsigned wb0 = cvt_pk_bf16(s[R0 + 4], s[R0 + 5]);
        const unsigned wb1 = cvt_pk_bf16(s[R0 + 6], s[R0 + 7]);
        const int s0 = hi ? (int)wa0 : (int)wb0;
        const int s1 = hi ? (int)wa1 : (int)wb1;
        const int r0 = __shfl_xor(s0, 32, 64);
        const int r1 = __shfl_xor(s1, 32, 64);
        int4 u;
        u.x = hi ? r0 : (int)wa0;
        u.y = hi ? r1 : (int)wa1;
        u.z = hi ? (int)wb0 : r0;
        u.w = hi ? (int)wb1 : r1;
        pf[kb] = *(bf16x8*)&u;
      }

      const u16* VB = Vl[cur];
      __builtin_amdgcn_s_setprio(1);
      #pragma unroll
      for (int db = 0; db < 4; ++db){
        const int r6 = (db & 1) * 32 + l31;   // row in V image
        const int hd = db >> 1;
        #pragma unroll
        for (int kb = 0; kb < 2; ++kb){
          const int sp = ((hd * 4 + kb * 2 + hi) ^ sw7) * 8;
          bf16x8 vf = *(const bf16x8*)(VB + r6 * 64 + sp);
          o[db] = __builtin_amdgcn_mfma_f32_32x32x16_bf16(vf, pf[kb], o[db], 0, 0, 0);
        }
      }
      __builtin_amdgcn_s_setprio(0);
    }

    ++cur; if (cur == 3) cur = 0;
  }

  const float lt = lsum + __shfl_xor(lsum, 32, 64);
  const float inv = 1.0f / lt;
  u16* op = aout + (size_t)(b * TT + qg) * HID + h * 128;
  #pragma unroll
  for (int db = 0; db < 4; ++db)
    #pragma unroll
    for (int rq = 0; rq < 4; ++rq){
      ushort4 pk;
      pk.x = f2bf(o[db][rq * 4 + 0] * inv);
      pk.y = f2bf(o[db][rq * 4 + 1] * inv);
      pk.z = f2bf(o[db][rq * 4 + 2] * inv);
      pk.w = f2bf(o[db][rq * 4 + 3] * inv);
      *(ushort4*)(op + db * 32 + rq * 8 + hi * 4) = pk;
    }
}

// ---------------- host launch ----------------
extern "C" void kernel_launch(void* const* d_in, const int* in_sizes, int n_in,
                              void* d_out, int out_size, void* d_ws, size_t ws_size,
                              hipStream_t stream)
{
  (void)in_sizes; (void)n_in; (void)out_size; (void)ws_size;
  const float* hs    = (const float*)d_in[0];
  const float* w_qkv = (const float*)d_in[1];
  const float* w_out = (const float*)d_in[2];
  const float* b_out = (const float*)d_in[3];
  float* out = (float*)d_out;

  char* ws = (char*)d_ws;
  u16* qkv_bf  = (u16*)(ws);
  u16* wout_bf = (u16*)(ws + 100663296);
  u16* hs_bf   = (u16*)(ws + 109051904);
  u16* attn_bf = hs_bf;
  u16* wqkv_bf = (u16*)(ws + 142606336);
  u16* vt2_bf  = wqkv_bf;

  cvt_all<<<4096, 256, 0, stream>>>(hs,    hs_bf,   (BT * HID) / 4,
                                    w_qkv, wqkv_bf, (QKV_N * HID) / 4,
                                    w_out, wout_bf, (HID * 2048) / 4);

  gemm256<1><<<(BT / 256) * (QKV_N / 256), 512, 0, stream>>>(
      hs_bf, wqkv_bf, qkv_bf, nullptr, nullptr, BT, QKV_N, HID);

  vtrans<<<dim3(TT / 32, 64), 256, 0, stream>>>(qkv_bf, vt2_bf);

  attn<<<dim3(64, 16), 256, 0, stream>>>(qkv_bf, vt2_bf, attn_bf);

  gemm256<0><<<(BT / 256) * (HID / 256), 512, 0, stream>>>(
      attn_bf, wout_bf, nullptr, out, b_out, BT, HID, HID);
}

// Round 11
// 362.475 us; speedup vs baseline: 1.0707x; 1.0707x over previous
//
#include <hip/hip_runtime.h>
#include <hip/hip_bf16.h>
#include <stdint.h>

#define HID   2048
#define NH    16
#define QKV_N 6144   // 16*(2*128+128)
#define QKP   4096   // pitch of qk_bf (Q|K only)
#define BT    8192   // B*T
#define TT    2048   // T

typedef short bf16x8  __attribute__((ext_vector_type(8)));
typedef float f32x4   __attribute__((ext_vector_type(4)));
typedef float f32x16  __attribute__((ext_vector_type(16)));
typedef unsigned short u16;

__device__ __forceinline__ u16 f2bf(float f){
  union { float f; unsigned u; } v; v.f = f;
  unsigned r = 0x7fffu + ((v.u >> 16) & 1u);
  return (u16)((v.u + r) >> 16);
}
__device__ __forceinline__ float bf2f(u16 x){
  union { unsigned u; float f; } v; v.u = ((unsigned)x) << 16;
  return v.f;
}
__device__ __forceinline__ unsigned cvt_pk_bf16(float lo, float hi){
  unsigned r;
  asm("v_cvt_pk_bf16_f32 %0, %1, %2" : "=v"(r) : "v"(lo), "v"(hi));
  return r;
}

typedef __attribute__((address_space(3))) void lds_vt;
typedef const __attribute__((address_space(1))) void gbl_vt;

__device__ __forceinline__ void gload16(const void* g, void* l){
  __builtin_amdgcn_global_load_lds((gbl_vt*)g, (lds_vt*)l, 16, 0, 0);
}

#define FENCE() asm volatile("" ::: "memory")
#define SYNC()  { FENCE(); __builtin_amdgcn_s_barrier(); FENCE(); }

// ---------------- fused fp32 -> bf16 convert (3 arrays, 1 launch) ----------------
__global__ __launch_bounds__(256) void cvt_all(const float* __restrict__ in1, u16* __restrict__ o1, int n1,
                                               const float* __restrict__ in2, u16* __restrict__ o2, int n2,
                                               const float* __restrict__ in3, u16* __restrict__ o3, int n3){
  int i = blockIdx.x * blockDim.x + threadIdx.x;
  const int stride = gridDim.x * blockDim.x;
  const int ntot = n1 + n2 + n3;
  for (; i < ntot; i += stride){
    const float* ip; u16* op; int k;
    if (i < n1)            { ip = in1; op = o1; k = i; }
    else if (i < n1 + n2)  { ip = in2; op = o2; k = i - n1; }
    else                   { ip = in3; op = o3; k = i - n1 - n2; }
    float4 v = ((const float4*)ip)[k];
    ushort4 o;
    o.x = f2bf(v.x); o.y = f2bf(v.y); o.z = f2bf(v.z); o.w = f2bf(v.w);
    ((ushort4*)op)[k] = o;
  }
}

// ---------------- 256x256 8-phase bf16 GEMM, C = A * B^T ----------------
// 16x16x32 core (known-good: 186us, MfmaUtil 50%, 0 conflicts).
// MODE 0: fp32 out + bias (pitch N). MODE 1: bf16 out, Q/K tiles (n0<4096) ->
// Cb pitch 4096; V tiles (n0>=4096) -> vt2 transposed-swizzled image (fused vtrans).
template<int MODE>
__global__ __launch_bounds__(512, 2) void gemm256(const u16* __restrict__ A,
                                                  const u16* __restrict__ Bm,
                                                  u16* __restrict__ Cb,
                                                  float* __restrict__ Cf,
                                                  const float* __restrict__ bias,
                                                  u16* __restrict__ vt2,
                                                  int M, int N, int K)
{
  __shared__ u16 lds[4 * 256 * 64];   // 128 KiB
  u16* const Abuf[2] = { lds,          lds + 16384 };
  u16* const Bbuf[2] = { lds + 32768,  lds + 49152 };

  const int tid  = threadIdx.x;
  const int w    = tid >> 6;
  const int lane = tid & 63;
  const int wm   = w >> 2;
  const int wn   = w & 3;
  const int lr   = lane & 15;
  const int lg   = lane >> 4;

  int bid = blockIdx.x;
  { int qq = gridDim.x >> 3; bid = (bid & 7) * qq + (bid >> 3); }
  const int ntile = N >> 8;
  const int m0 = (bid / ntile) << 8;
  const int n0 = (bid % ntile) << 8;

  const int rS = tid >> 3;
  const int cS = ((tid & 7) ^ (rS & 7)) * 8;
  const u16* gA = A  + (size_t)(m0 + rS) * K + cS;
  const u16* gB = Bm + (size_t)(n0 + rS) * K + cS;
  const int wds = w * 512;

  f32x4 acc[8][4] = {};
  bf16x8 aq[2][2], bq[4][2];

  auto stgA = [&](int buf, int half, int kt){
    const u16* s = gA + (size_t)(half * 128) * K + (size_t)kt * 64;
    gload16(s,                  Abuf[buf] + half * 8192 + wds);
    gload16(s + (size_t)64 * K, Abuf[buf] + half * 8192 + 4096 + wds);
  };
  auto stgB = [&](int buf, int half, int kt){
    const u16* s = gB + (size_t)(half * 128) * K + (size_t)kt * 64;
    gload16(s,                  Bbuf[buf] + half * 8192 + wds);
    gload16(s + (size_t)64 * K, Bbuf[buf] + half * 8192 + 4096 + wds);
  };
  auto loadA = [&](const u16* ab, int q){
    #pragma unroll
    for (int kk = 0; kk < 2; ++kk){
      #pragma unroll
      for (int mf2 = 0; mf2 < 2; ++mf2){
        int row = wm * 128 + (q * 2 + mf2) * 16 + lr;
        int blk = (kk * 4 + lg) ^ (lr & 7);
        aq[mf2][kk] = *(const bf16x8*)(ab + row * 64 + blk * 8);
      }
    }
  };
  auto loadB = [&](const u16* bb){
    #pragma unroll
    for (int nf = 0; nf < 4; ++nf){
      #pragma unroll
      for (int kk = 0; kk < 2; ++kk){
        int row = wn * 64 + nf * 16 + lr;
        int blk = (kk * 4 + lg) ^ (lr & 7);
        bq[nf][kk] = *(const bf16x8*)(bb + row * 64 + blk * 8);
      }
    }
  };

#define MFMAQ(Q) do {                                                         \
    __builtin_amdgcn_s_setprio(1);                                            \
    _Pragma("unroll")                                                         \
    for (int kk = 0; kk < 2; ++kk){                                           \
      _Pragma("unroll")                                                       \
      for (int mf2 = 0; mf2 < 2; ++mf2){                                      \
        _Pragma("unroll")                                                     \
        for (int nf = 0; nf < 4; ++nf)                                        \
          acc[(Q)*2+mf2][nf] = __builtin_amdgcn_mfma_f32_16x16x32_bf16(       \
              aq[mf2][kk], bq[nf][kk], acc[(Q)*2+mf2][nf], 0, 0, 0);          \
      }                                                                       \
    }                                                                         \
    __builtin_amdgcn_s_setprio(0);                                            \
  } while (0)

  stgA(0, 0, 0); stgA(0, 1, 0);
  stgB(0, 0, 0); stgB(0, 1, 0);
  stgB(1, 0, 1); stgB(1, 1, 1);
  asm volatile("s_waitcnt vmcnt(4)" ::: "memory");
  SYNC();

  const int NI = K >> 7;
  for (int it = 0; it < NI; ++it){
    const int t = it * 2;
    const bool lastI = (it == NI - 1);

    loadB(Bbuf[0]);
    loadA(Abuf[0], 0);
    stgA(1, 0, t + 1);
    SYNC(); MFMAQ(0); SYNC();

    loadA(Abuf[0], 1);
    stgA(1, 1, t + 1);
    SYNC(); MFMAQ(1); SYNC();

    loadA(Abuf[0], 2);
    if (!lastI) stgB(0, 0, t + 2);
    SYNC(); MFMAQ(2); SYNC();

    loadA(Abuf[0], 3);
    if (!lastI) stgB(0, 1, t + 2);
    SYNC(); MFMAQ(3);
    if (lastI) asm volatile("s_waitcnt vmcnt(0)" ::: "memory");
    else       asm volatile("s_waitcnt vmcnt(4)" ::: "memory");
    SYNC();

    loadB(Bbuf[1]);
    loadA(Abuf[1], 0);
    if (!lastI) stgA(0, 0, t + 2);
    SYNC(); MFMAQ(0); SYNC();

    loadA(Abuf[1], 1);
    if (!lastI) stgA(0, 1, t + 2);
    SYNC(); MFMAQ(1); SYNC();

    loadA(Abuf[1], 2);
    if (!lastI) stgB(1, 0, t + 3);
    SYNC(); MFMAQ(2); SYNC();

    loadA(Abuf[1], 3);
    if (!lastI) stgB(1, 1, t + 3);
    SYNC(); MFMAQ(3);
    if (!lastI) asm volatile("s_waitcnt vmcnt(4)" ::: "memory");
    SYNC();
  }
#undef MFMAQ

  // epilogue: D layout col = lane&15, row = (lane>>4)*4 + r
  const int orow = m0 + wm * 128 + lg * 4;
  const int ocol = n0 + wn * 64 + lr;

  if (MODE == 1 && n0 >= 4096){
    // fused V-transpose: write vt2[bh][t5] image (exact inverse of attn's reader)
    #pragma unroll
    for (int nf = 0; nf < 4; ++nf){
      const int c   = ocol + nf * 16 - 4096;   // 0..2047
      const int h2  = c >> 7;
      const int d   = c & 127;
      const int r64 = d & 63;
      const int hd  = d >> 6;
      #pragma unroll
      for (int mf = 0; mf < 8; ++mf)
        #pragma unroll
        for (int r = 0; r < 4; ++r){
          const int row = orow + mf * 16 + r;       // t_global
          const int bb  = row >> 11;
          const int t   = row & 2047;
          const int t5  = t >> 5;
          const int kv  = t & 31;
          const int sl  = hd * 4 + (kv >> 3);
          const int sp  = sl ^ (r64 & 7);
          vt2[(size_t)((bb * 16 + h2) * 64 + t5) * 4096 + r64 * 64 + sp * 8 + (kv & 7)]
              = f2bf(acc[mf][nf][r]);
        }
    }
  } else {
    #pragma unroll
    for (int mf = 0; mf < 8; ++mf)
      #pragma unroll
      for (int nf = 0; nf < 4; ++nf)
        #pragma unroll
        for (int r = 0; r < 4; ++r){
          int row = orow + mf * 16 + r;
          int col = ocol + nf * 16;
          float v = acc[mf][nf][r];
          if (MODE == 1)
            Cb[(size_t)row * QKP + col] = f2bf(v);
          else
            Cf[(size_t)row * N + col] = v + bias[col];
        }
  }
}

// ---------------- causal flash attention, swapped 32x32, KVBLK=32 ----------------
// Q/K from qk_bf (pitch 4096); V from vt2 image. Triple-buffered (48KB, 3 blk/CU).
__global__ __launch_bounds__(256, 3) void attn(const u16* __restrict__ qk,
                                               const u16* __restrict__ vt2,
                                               u16* __restrict__ aout)
{
  __shared__ u16 Kl[3][32 * 128];   // 24KB
  __shared__ u16 Vl[3][64 * 64];    // 24KB

  const int qt = 15 - (int)blockIdx.y;
  const int bh = blockIdx.x;
  const int b = bh >> 4, h = bh & 15;
  const int tid  = threadIdx.x;
  const int w    = tid >> 6;
  const int lane = tid & 63;
  const int l31  = lane & 31;
  const int hi   = lane >> 5;
  const int sw7  = l31 & 7;

  const int qg = qt * 128 + w * 32 + l31;   // this lane's q row
  const float sc2 = 0.08838834764831845f * 1.4426950408889634f;

  bf16x8 qf[8];
  {
    const u16* qp = qk + (size_t)(b * TT + qg) * QKP + h * 128 + hi * 8;
    #pragma unroll
    for (int s = 0; s < 8; ++s){
      bf16x8 raw = *(const bf16x8*)(qp + s * 16);
      unsigned pk[4];
      #pragma unroll
      for (int p2 = 0; p2 < 4; ++p2)
        pk[p2] = cvt_pk_bf16(bf2f((u16)raw[2 * p2]) * sc2,
                             bf2f((u16)raw[2 * p2 + 1]) * sc2);
      int4 u = { (int)pk[0], (int)pk[1], (int)pk[2], (int)pk[3] };
      qf[s] = *(bf16x8*)&u;
    }
  }

  f32x16 o[4] = {};
  float lsum = 0.f;

  const u16* ksrc = qk + (size_t)(b * TT + (tid >> 4)) * QKP + 2048 + h * 128
                    + (((tid & 15) ^ ((tid >> 4) & 7)) * 8);
  const u16* vsrc = vt2 + (size_t)bh * (64 * 4096) + tid * 8;

  auto stage = [&](int buf, int j){
    const u16* ks = ksrc + (size_t)(j * 32) * QKP;
    gload16(ks,                    &Kl[buf][tid * 8]);
    gload16(ks + (size_t)16 * QKP, &Kl[buf][2048 + tid * 8]);
    const u16* vs = vsrc + (size_t)j * 4096;
    gload16(vs,        &Vl[buf][tid * 8]);
    gload16(vs + 2048, &Vl[buf][2048 + tid * 8]);
  };

  const int NT  = 4 * qt + 4;       // >= 4
  const int jme = qt * 4 + w;       // last tile this wave computes (diagonal)
  stage(0, 0);
  stage(1, 1);

  int cur = 0;
  for (int j = 0; j < NT; ++j){
    SYNC();                                   // B1: buf[(j+2)%3]'s readers done
    if (j + 2 < NT){
      int nb = cur + 2; if (nb >= 3) nb -= 3;
      stage(nb, j + 2);
      asm volatile("s_waitcnt vmcnt(8)" ::: "memory");   // stage(j) landed
    } else if (j + 1 < NT){
      asm volatile("s_waitcnt vmcnt(4)" ::: "memory");
    } else {
      asm volatile("s_waitcnt vmcnt(0)" ::: "memory");
    }
    SYNC();                                   // B2: buf[cur] visible

    if (j <= jme){
      f32x16 sa = {}, sb = {};
      const u16* KB = Kl[cur];
      __builtin_amdgcn_s_setprio(1);
      #pragma unroll
      for (int sl = 0; sl < 4; ++sl){
        const int spa = ((sl * 2 + hi) ^ sw7) * 8;
        const int spb = (((sl + 4) * 2 + hi) ^ sw7) * 8;
        bf16x8 ka = *(const bf16x8*)(KB + l31 * 128 + spa);
        bf16x8 kb2 = *(const bf16x8*)(KB + l31 * 128 + spb);
        sa = __builtin_amdgcn_mfma_f32_32x32x16_bf16(ka,  qf[sl],     sa, 0, 0, 0);
        sb = __builtin_amdgcn_mfma_f32_32x32x16_bf16(kb2, qf[sl + 4], sb, 0, 0, 0);
      }
      __builtin_amdgcn_s_setprio(0);

      f32x16 s;
      #pragma unroll
      for (int r = 0; r < 16; ++r) s[r] = sa[r] + sb[r];

      if (j == jme){
        #pragma unroll
        for (int r = 0; r < 16; ++r){
          const int krow = (r & 3) + 8 * (r >> 2) + 4 * hi;
          if (krow > l31) s[r] = -3.0e38f;
        }
      }

      #pragma unroll
      for (int r = 0; r < 16; ++r) s[r] = exp2f(s[r]);
      {
        float t0 = (s[0] + s[1]) + (s[2] + s[3]);
        float t1 = (s[4] + s[5]) + (s[6] + s[7]);
        float t2 = (s[8] + s[9]) + (s[10] + s[11]);
        float t3 = (s[12] + s[13]) + (s[14] + s[15]);
        lsum += (t0 + t1) + (t2 + t3);
      }

      bf16x8 pf[2];
      #pragma unroll
      for (int kb = 0; kb < 2; ++kb){
        const int R0 = kb * 8;
        const unsigned wa0 = cvt_pk_bf16(s[R0],     s[R0 + 1]);
        const unsigned wa1 = cvt_pk_bf16(s[R0 + 2], s[R0 + 3]);
        const unsigned wb0 = cvt_pk_bf16(s[R0 + 4], s[R0 + 5]);
        const unsigned wb1 = cvt_pk_bf16(s[R0 + 6], s[R0 + 7]);
        const int s0 = hi ? (int)wa0 : (int)wb0;
        const int s1 = hi ? (int)wa1 : (int)wb1;
        const int r0 = __shfl_xor(s0, 32, 64);
        const int r1 = __shfl_xor(s1, 32, 64);
        int4 u;
        u.x = hi ? r0 : (int)wa0;
        u.y = hi ? r1 : (int)wa1;
        u.z = hi ? (int)wb0 : r0;
        u.w = hi ? (int)wb1 : r1;
        pf[kb] = *(bf16x8*)&u;
      }

      const u16* VB = Vl[cur];
      __builtin_amdgcn_s_setprio(1);
      #pragma unroll
      for (int db = 0; db < 4; ++db){
        const int r6 = (db & 1) * 32 + l31;   // row in V image
        const int hd = db >> 1;
        #pragma unroll
        for (int kb = 0; kb < 2; ++kb){
          const int sp = ((hd * 4 + kb * 2 + hi) ^ sw7) * 8;
          bf16x8 vf = *(const bf16x8*)(VB + r6 * 64 + sp);
          o[db] = __builtin_amdgcn_mfma_f32_32x32x16_bf16(vf, pf[kb], o[db], 0, 0, 0);
        }
      }
      __builtin_amdgcn_s_setprio(0);
    }

    ++cur; if (cur == 3) cur = 0;
  }

  const float lt = lsum + __shfl_xor(lsum, 32, 64);
  const float inv = 1.0f / lt;
  u16* op = aout + (size_t)(b * TT + qg) * HID + h * 128;
  #pragma unroll
  for (int db = 0; db < 4; ++db)
    #pragma unroll
    for (int rq = 0; rq < 4; ++rq){
      ushort4 pk;
      pk.x = f2bf(o[db][rq * 4 + 0] * inv);
      pk.y = f2bf(o[db][rq * 4 + 1] * inv);
      pk.z = f2bf(o[db][rq * 4 + 2] * inv);
      pk.w = f2bf(o[db][rq * 4 + 3] * inv);
      *(ushort4*)(op + db * 32 + rq * 8 + hi * 4) = pk;
    }
}

// ---------------- host launch ----------------
extern "C" void kernel_launch(void* const* d_in, const int* in_sizes, int n_in,
                              void* d_out, int out_size, void* d_ws, size_t ws_size,
                              hipStream_t stream)
{
  (void)in_sizes; (void)n_in; (void)out_size; (void)ws_size;
  const float* hs    = (const float*)d_in[0];
  const float* w_qkv = (const float*)d_in[1];
  const float* w_out = (const float*)d_in[2];
  const float* b_out = (const float*)d_in[3];
  float* out = (float*)d_out;

  char* ws = (char*)d_ws;
  // layout: qk_bf [8192][4096] @0 (67,108,864) | vt2 @67,108,864 (33,554,432)
  //         wout @100,663,296 (8,388,608) | hs/attn @109,051,904 (33,554,432)
  //         wqkv @142,606,336 (25,165,824)   -- total 167,772,160 (same as before)
  u16* qk_bf   = (u16*)(ws);
  u16* vt2_bf  = (u16*)(ws + 67108864);
  u16* wout_bf = (u16*)(ws + 100663296);
  u16* hs_bf   = (u16*)(ws + 109051904);
  u16* attn_bf = hs_bf;
  u16* wqkv_bf = (u16*)(ws + 142606336);

  cvt_all<<<4096, 256, 0, stream>>>(hs,    hs_bf,   (BT * HID) / 4,
                                    w_qkv, wqkv_bf, (QKV_N * HID) / 4,
                                    w_out, wout_bf, (HID * 2048) / 4);

  gemm256<1><<<(BT / 256) * (QKV_N / 256), 512, 0, stream>>>(
      hs_bf, wqkv_bf, qk_bf, nullptr, nullptr, vt2_bf, BT, QKV_N, HID);

  attn<<<dim3(64, 16), 256, 0, stream>>>(qk_bf, vt2_bf, attn_bf);

  gemm256<0><<<(BT / 256) * (HID / 256), 512, 0, stream>>>(
      attn_bf, wout_bf, nullptr, out, b_out, nullptr, BT, HID, HID);
}